// Round 1
// baseline (317.027 us; speedup 1.0000x reference)
//
#include <hip/hip_runtime.h>
#include <hip/hip_bf16.h>
#include <stdint.h>

typedef __bf16 bf16;
typedef __bf16 bf16x8 __attribute__((ext_vector_type(8)));
typedef __bf16 bf16x4 __attribute__((ext_vector_type(4)));
typedef float f32x4 __attribute__((ext_vector_type(4)));

#define DEV static __device__ __forceinline__

// ---------------------------------------------------------------------------
// dtype detector: bf16 tensors have ~all uint16 exponent fields near 127;
// fp32 tensors look bf16-like only in the top halves (~50%) plus ~7% noise.
// bf16 -> cnt ~63/64 ; fp32 -> cnt ~34/64. Threshold 50.
// ---------------------------------------------------------------------------
DEV bool detect_bf16(const void* p) {
    const uint16_t* u = (const uint16_t*)p;
    int cnt = 0;
    #pragma unroll
    for (int i = 0; i < 64; ++i) {
        int e = (u[i] >> 7) & 0xFF;          // bf16 exponent field
        cnt += (e >= 116 && e <= 134) ? 1 : 0;
    }
    return cnt >= 50;
}

DEV float fast_softplus(float v) {
    // softplus(v) = max(v,0) + log1p(exp(-|v|)), via exp2/log2 HW ops
    float e = __builtin_amdgcn_exp2f(fabsf(v) * -1.4426950408889634f);
    float l = __builtin_amdgcn_logf(1.0f + e) * 0.6931471805599453f;
    return fmaxf(v, 0.0f) + l;
}

DEV void async_lds16(const void* g, void* l) {
    __builtin_amdgcn_global_load_lds(
        (const __attribute__((address_space(1))) void*)g,
        (__attribute__((address_space(3))) void*)l, 16, 0, 0);
}

// log_sigma scalar (true value 1.0 here). fp32 1.0 -> low 16 bits are 0x0000
// so the bf16 probe reads 0 and we fall through to the fp32 read.
DEV float read_ls(const void* p) {
    float vb = (float)((const bf16*)p)[0];
    if (vb != 0.0f && fabsf(vb) < 16.0f) return vb;
    float vf = ((const float*)p)[0];
    return (fabsf(vf) < 16.0f) ? vf : 0.0f;
}

#define MFMA16(a, b, c) __builtin_amdgcn_mfma_f32_16x16x32_bf16((a), (b), (c), 0, 0, 0)

// ws layout (bytes):
//   FX   @ 0        : [16384][128] bf16  (phi(x) rows 0..8191, phi(z) rows 8192..)
//   SQ   @ 4194304  : [16384] fp32 row sq-norms (of the rounded FX)
//   WB   @ 4259840  : [49152] bf16  = [w1 | w2 | w3 | sk]
//   BIAS @ 4358144  : [384] fp32    = [b1 | b2 | b3]
#define FX_OFF   0
#define SQ_OFF   4194304
#define WB_OFF   4259840
#define BIAS_OFF 4358144

// ---------------------------------------------------------------------------
// prep: convert weights (any dtype) -> bf16 WB, biases -> fp32 BIAS
// ---------------------------------------------------------------------------
__global__ __launch_bounds__(256) void prep_k(
    const void* __restrict__ w1, const void* __restrict__ b1,
    const void* __restrict__ w2, const void* __restrict__ b2,
    const void* __restrict__ w3, const void* __restrict__ b3,
    const void* __restrict__ sk,
    bf16* __restrict__ WB, float* __restrict__ BIAS)
{
    int tid = blockIdx.x * 256 + threadIdx.x;
    if (tid < 49152) {
        const void* s; int j;
        if (tid < 8192)       { s = w1; j = tid; }
        else if (tid < 24576) { s = w2; j = tid - 8192; }
        else if (tid < 40960) { s = w3; j = tid - 24576; }
        else                  { s = sk; j = tid - 40960; }
        bool isbf = detect_bf16(s);
        float v = isbf ? (float)((const bf16*)s)[j] : ((const float*)s)[j];
        WB[tid] = (bf16)v;
    } else if (tid < 49536) {
        int k = tid - 49152;
        const void* s = (k < 128) ? b1 : (k < 256) ? b2 : b3;
        int j = k & 127;
        bool isbf = detect_bf16(s);
        BIAS[k] = isbf ? (float)((const bf16*)s)[j] : ((const float*)s)[j];
    }
}

// ---------------------------------------------------------------------------
// Phase 1: fused 3-layer MLP + skip for 32 rows/block.
// H LDS row (stride 200 bf16): cols [0,128) = h, cols [128,192) = input row X
// (so layer3 folds the skip as concatenated K: C3 = [h2 | X] @ [W3 | Sk]^T).
// ---------------------------------------------------------------------------
#define HSTR 200

__global__ __launch_bounds__(256) void mlp_k(
    const void* __restrict__ xv, const void* __restrict__ zv,
    const bf16* __restrict__ WB, const float* __restrict__ BIAS,
    bf16* __restrict__ FX, float* __restrict__ SQ)
{
    __shared__ bf16 H[32 * HSTR];
    __shared__ float sqp[32][4];

    const int t    = threadIdx.x;
    const int lane = t & 63;
    const int w    = t >> 6;
    const int l15  = lane & 15;
    const int quad = lane >> 4;
    const int colw = w * 32;                 // this wave's 32 output cols
    const int row0 = blockIdx.x * 32;

    const void*  src   = (row0 < 8192) ? xv : zv;
    const size_t rbase = (row0 < 8192) ? (size_t)row0 * 64
                                       : (size_t)(row0 - 8192) * 64;
    const bool isbf = detect_bf16(src);

    // stage X tile (32 rows x 64) as bf16 into H[., 128..191]; 8 elems/thread
    {
        int r = t >> 3, g = t & 7;
        bf16 v8[8];
        if (isbf) {
            *(uint4*)v8 = *(const uint4*)((const bf16*)src + rbase + r * 64 + g * 8);
        } else {
            const float* f = (const float*)src + rbase + r * 64 + g * 8;
            float4 a = *(const float4*)f;
            float4 b = *(const float4*)(f + 4);
            v8[0] = (bf16)a.x; v8[1] = (bf16)a.y; v8[2] = (bf16)a.z; v8[3] = (bf16)a.w;
            v8[4] = (bf16)b.x; v8[5] = (bf16)b.y; v8[6] = (bf16)b.z; v8[7] = (bf16)b.w;
        }
        *(uint4*)&H[r * HSTR + 128 + g * 8] = *(uint4*)v8;
    }
    __syncthreads();

    const bf16* W1 = WB;
    const bf16* W2 = WB + 8192;
    const bf16* W3 = WB + 24576;
    const bf16* SK = WB + 40960;

    f32x4 acc[2][2];

    // ---------------- layer 1: K=64 (X region), B = w1 [128][64] -------------
    #pragma unroll
    for (int mi = 0; mi < 2; ++mi)
        #pragma unroll
        for (int ni = 0; ni < 2; ++ni)
            acc[mi][ni] = f32x4{0.f, 0.f, 0.f, 0.f};
    #pragma unroll
    for (int ks = 0; ks < 2; ++ks) {
        int ko = ks * 32 + quad * 8;
        bf16x8 a0 = *(const bf16x8*)&H[(l15)      * HSTR + 128 + ko];
        bf16x8 a1 = *(const bf16x8*)&H[(16 + l15) * HSTR + 128 + ko];
        bf16x8 bb0 = *(const bf16x8*)(W1 + (colw + l15)      * 64 + ko);
        bf16x8 bb1 = *(const bf16x8*)(W1 + (colw + 16 + l15) * 64 + ko);
        acc[0][0] = MFMA16(a0, bb0, acc[0][0]);
        acc[0][1] = MFMA16(a0, bb1, acc[0][1]);
        acc[1][0] = MFMA16(a1, bb0, acc[1][0]);
        acc[1][1] = MFMA16(a1, bb1, acc[1][1]);
    }
    {
        float bv0 = BIAS[colw + l15];
        float bv1 = BIAS[colw + 16 + l15];
        #pragma unroll
        for (int mi = 0; mi < 2; ++mi)
            #pragma unroll
            for (int p = 0; p < 4; ++p) {
                int r = mi * 16 + quad * 4 + p;
                H[r * HSTR + colw + l15]      = (bf16)fast_softplus(acc[mi][0][p] + bv0);
                H[r * HSTR + colw + 16 + l15] = (bf16)fast_softplus(acc[mi][1][p] + bv1);
            }
    }
    __syncthreads();

    // ---------------- layer 2: K=128 (h region), B = w2 [128][128] -----------
    #pragma unroll
    for (int mi = 0; mi < 2; ++mi)
        #pragma unroll
        for (int ni = 0; ni < 2; ++ni)
            acc[mi][ni] = f32x4{0.f, 0.f, 0.f, 0.f};
    #pragma unroll
    for (int ks = 0; ks < 4; ++ks) {
        int ko = ks * 32 + quad * 8;
        bf16x8 a0 = *(const bf16x8*)&H[(l15)      * HSTR + ko];
        bf16x8 a1 = *(const bf16x8*)&H[(16 + l15) * HSTR + ko];
        bf16x8 bb0 = *(const bf16x8*)(W2 + (colw + l15)      * 128 + ko);
        bf16x8 bb1 = *(const bf16x8*)(W2 + (colw + 16 + l15) * 128 + ko);
        acc[0][0] = MFMA16(a0, bb0, acc[0][0]);
        acc[0][1] = MFMA16(a0, bb1, acc[0][1]);
        acc[1][0] = MFMA16(a1, bb0, acc[1][0]);
        acc[1][1] = MFMA16(a1, bb1, acc[1][1]);
    }
    __syncthreads();   // all reads of h1 done before overwrite
    {
        float bv0 = BIAS[128 + colw + l15];
        float bv1 = BIAS[128 + colw + 16 + l15];
        #pragma unroll
        for (int mi = 0; mi < 2; ++mi)
            #pragma unroll
            for (int p = 0; p < 4; ++p) {
                int r = mi * 16 + quad * 4 + p;
                H[r * HSTR + colw + l15]      = (bf16)fast_softplus(acc[mi][0][p] + bv0);
                H[r * HSTR + colw + 16 + l15] = (bf16)fast_softplus(acc[mi][1][p] + bv1);
            }
    }
    __syncthreads();

    // ------- layer 3: K=192 ([h2 | X]), B = [w3 | skip_w], + b3 -> FX, SQ ----
    #pragma unroll
    for (int mi = 0; mi < 2; ++mi)
        #pragma unroll
        for (int ni = 0; ni < 2; ++ni)
            acc[mi][ni] = f32x4{0.f, 0.f, 0.f, 0.f};
    #pragma unroll
    for (int ks = 0; ks < 6; ++ks) {
        int ko = ks * 32 + quad * 8;
        bf16x8 a0 = *(const bf16x8*)&H[(l15)      * HSTR + ko];
        bf16x8 a1 = *(const bf16x8*)&H[(16 + l15) * HSTR + ko];
        const bf16 *p0, *p1;
        if (ks < 4) {
            p0 = W3 + (colw + l15)      * 128 + ko;
            p1 = W3 + (colw + 16 + l15) * 128 + ko;
        } else {
            int ko2 = (ks - 4) * 32 + quad * 8;
            p0 = SK + (colw + l15)      * 64 + ko2;
            p1 = SK + (colw + 16 + l15) * 64 + ko2;
        }
        bf16x8 bb0 = *(const bf16x8*)p0;
        bf16x8 bb1 = *(const bf16x8*)p1;
        acc[0][0] = MFMA16(a0, bb0, acc[0][0]);
        acc[0][1] = MFMA16(a0, bb1, acc[0][1]);
        acc[1][0] = MFMA16(a1, bb0, acc[1][0]);
        acc[1][1] = MFMA16(a1, bb1, acc[1][1]);
    }
    {
        float bv0 = BIAS[256 + colw + l15];
        float bv1 = BIAS[256 + colw + 16 + l15];
        #pragma unroll
        for (int mi = 0; mi < 2; ++mi)
            #pragma unroll
            for (int p = 0; p < 4; ++p) {
                int r = mi * 16 + quad * 4 + p;
                float v0 = acc[mi][0][p] + bv0;
                float v1 = acc[mi][1][p] + bv1;
                bf16 q0 = (bf16)v0, q1 = (bf16)v1;
                FX[(size_t)(row0 + r) * 128 + colw + l15]      = q0;
                FX[(size_t)(row0 + r) * 128 + colw + 16 + l15] = q1;
                // sq from the *rounded* values so diff is an exact sq-distance
                float f0 = (float)q0, f1 = (float)q1;
                float s = fmaf(f0, f0, f1 * f1);
                s += __shfl_xor(s, 1, 16);
                s += __shfl_xor(s, 2, 16);
                s += __shfl_xor(s, 4, 16);
                s += __shfl_xor(s, 8, 16);
                if (l15 == 0) sqp[r][w] = s;
            }
    }
    __syncthreads();
    if (t < 32) SQ[row0 + t] = sqp[t][0] + sqp[t][1] + sqp[t][2] + sqp[t][3];
}

// ---------------------------------------------------------------------------
// Phase 2: 128x128 C-tile per block, K=128 staged once via global_load_lds.
// XOR-chunk swizzle on the GLOBAL fetch side: LDS chunk (r,c) holds global
// chunk (r, c^(r&7)); fragment reads un-swizzle with the same XOR.
//
// MFMA operands are SWAPPED (B-frag first): A/B fragment layouts of
// mfma_f32_16x16x32_bf16 are symmetric, and C/D layout is col=lane&15,
// row=(lane>>4)*4+reg. With the swap, lane&15 indexes the OUTPUT ROW and the
// 4 acc regs are 4 CONSECUTIVE OUTPUT COLUMNS -> one global_store_dwordx4
// (16 B/lane) per fragment instead of 4 scalar row-strided stores.
// Output stores are nontemporal: 268 MB stream must not thrash L2/FX tiles.
// ---------------------------------------------------------------------------
__global__ __launch_bounds__(256) void ker_k(
    const bf16* __restrict__ FX, const float* __restrict__ SQ,
    const void* __restrict__ lsp, const void* __restrict__ w1p,
    void* __restrict__ outv)
{
    __shared__ bf16 AT[128 * 128];
    __shared__ bf16 BT[128 * 128];

    const int t    = threadIdx.x;
    const int lane = t & 63;
    const int w    = t >> 6;
    const int l15  = lane & 15;
    const int quad = lane >> 4;
    const int wm   = w >> 1, wn = w & 1;
    const int brow = blockIdx.y, bcol = blockIdx.x;

    const bf16* Ag = FX + (size_t)brow * 128 * 128;            // fx tile
    const bf16* Bg = FX + (size_t)(8192 + bcol * 128) * 128;   // fz tile
    #pragma unroll
    for (int i = 0; i < 8; ++i) {
        int slot = (w * 8 + i) * 64 + lane;        // 16B-chunk slot in LDS
        int r = slot >> 4, c = slot & 15;
        int gc = (r << 4) | (c ^ (r & 7));         // swizzled source chunk
        async_lds16(Ag + gc * 8, &AT[(w * 8 + i) * 512]);
        async_lds16(Bg + gc * 8, &BT[(w * 8 + i) * 512]);
    }
    __syncthreads();

    f32x4 acc[4][4];
    #pragma unroll
    for (int mi = 0; mi < 4; ++mi)
        #pragma unroll
        for (int ni = 0; ni < 4; ++ni)
            acc[mi][ni] = f32x4{0.f, 0.f, 0.f, 0.f};

    #pragma unroll
    for (int ks = 0; ks < 4; ++ks) {
        bf16x8 a[4], b[4];
        #pragma unroll
        for (int mi = 0; mi < 4; ++mi) {
            int r  = wm * 64 + mi * 16 + l15;
            int cc = (ks * 4 + quad) ^ (r & 7);
            a[mi] = *(const bf16x8*)&AT[r * 128 + cc * 8];
        }
        #pragma unroll
        for (int ni = 0; ni < 4; ++ni) {
            int r  = wn * 64 + ni * 16 + l15;
            int cc = (ks * 4 + quad) ^ (r & 7);
            b[ni] = *(const bf16x8*)&BT[r * 128 + cc * 8];
        }
        // swapped operand order: D[row=fz-idx in regs][col=fx-idx at l15]
        // -> acc[mi][ni][p] = dot(FX row wm*64+mi*16+l15,
        //                         FZ row wn*64+ni*16+quad*4+p)
        #pragma unroll
        for (int mi = 0; mi < 4; ++mi)
            #pragma unroll
            for (int ni = 0; ni < 4; ++ni)
                acc[mi][ni] = MFMA16(b[ni], a[mi], acc[mi][ni]);
    }

    // epilogue: out = exp2(c2*sqx + c2*sqz - 2*c2*dot),  c2 = inv_bw*log2(e)
    const bool isbf = detect_bf16(w1p);   // output dtype follows problem dtype
    float ls  = read_ls(lsp);
    float p10 = __builtin_amdgcn_exp2f(ls * 3.321928094887362f);   // 10^ls
    float c2  = (-0.5f / p10) * 1.4426950408889634f;
    float m2  = -2.0f * c2;
    const float* sqx = SQ + (size_t)brow * 128;
    const float* sqz = SQ + 8192 + (size_t)bcol * 128;

    #pragma unroll
    for (int mi = 0; mi < 4; ++mi) {
        int rl = wm * 64 + mi * 16 + l15;               // per-lane output row
        float cq = c2 * sqx[rl];
        size_t grow = (size_t)(brow * 128 + rl) * 8192;
        #pragma unroll
        for (int ni = 0; ni < 4; ++ni) {
            int clb  = wn * 64 + ni * 16 + quad * 4;    // 4-col base
            int gcol = bcol * 128 + clb;
            f32x4 qz = *(const f32x4*)&sqz[clb];
            float e0 = __builtin_amdgcn_exp2f(fmaf(m2, acc[mi][ni][0], fmaf(c2, qz[0], cq)));
            float e1 = __builtin_amdgcn_exp2f(fmaf(m2, acc[mi][ni][1], fmaf(c2, qz[1], cq)));
            float e2 = __builtin_amdgcn_exp2f(fmaf(m2, acc[mi][ni][2], fmaf(c2, qz[2], cq)));
            float e3 = __builtin_amdgcn_exp2f(fmaf(m2, acc[mi][ni][3], fmaf(c2, qz[3], cq)));
            if (isbf) {
                bf16* o = (bf16*)outv;
                bf16x4 pv = { (bf16)e0, (bf16)e1, (bf16)e2, (bf16)e3 };
                __builtin_nontemporal_store(pv, (bf16x4*)(o + grow + gcol));
            } else {
                float* o = (float*)outv;
                f32x4 ev = { e0, e1, e2, e3 };
                __builtin_nontemporal_store(ev, (f32x4*)(o + grow + gcol));
            }
        }
    }
}

extern "C" void kernel_launch(void* const* d_in, const int* in_sizes, int n_in,
                              void* d_out, int out_size, void* d_ws, size_t ws_size,
                              hipStream_t stream) {
    bf16*  FX   = (bf16*) ((char*)d_ws + FX_OFF);
    float* SQ   = (float*)((char*)d_ws + SQ_OFF);
    bf16*  WB   = (bf16*) ((char*)d_ws + WB_OFF);
    float* BIAS = (float*)((char*)d_ws + BIAS_OFF);

    prep_k<<<194, 256, 0, stream>>>(d_in[2], d_in[3], d_in[4], d_in[5],
                                    d_in[6], d_in[7], d_in[8], WB, BIAS);
    mlp_k<<<512, 256, 0, stream>>>(d_in[0], d_in[1], WB, BIAS, FX, SQ);
    ker_k<<<dim3(64, 64), 256, 0, stream>>>(FX, SQ, d_in[9], d_in[2], d_out);
}

// Round 2
// 310.333 us; speedup vs baseline: 1.0216x; 1.0216x over previous
//
#include <hip/hip_runtime.h>
#include <hip/hip_bf16.h>
#include <stdint.h>

typedef __bf16 bf16;
typedef __bf16 bf16x8 __attribute__((ext_vector_type(8)));
typedef __bf16 bf16x4 __attribute__((ext_vector_type(4)));
typedef float f32x4 __attribute__((ext_vector_type(4)));

#define DEV static __device__ __forceinline__

// ---------------------------------------------------------------------------
// dtype detector: bf16 tensors have ~all uint16 exponent fields near 127;
// fp32 tensors look bf16-like only in the top halves (~50%) plus ~7% noise.
// bf16 -> cnt ~63/64 ; fp32 -> cnt ~34/64. Threshold 50.
// ---------------------------------------------------------------------------
DEV bool detect_bf16(const void* p) {
    const uint16_t* u = (const uint16_t*)p;
    int cnt = 0;
    #pragma unroll
    for (int i = 0; i < 64; ++i) {
        int e = (u[i] >> 7) & 0xFF;          // bf16 exponent field
        cnt += (e >= 116 && e <= 134) ? 1 : 0;
    }
    return cnt >= 50;
}

DEV float fast_softplus(float v) {
    // softplus(v) = max(v,0) + log1p(exp(-|v|)), via exp2/log2 HW ops
    float e = __builtin_amdgcn_exp2f(fabsf(v) * -1.4426950408889634f);
    float l = __builtin_amdgcn_logf(1.0f + e) * 0.6931471805599453f;
    return fmaxf(v, 0.0f) + l;
}

DEV void async_lds16(const void* g, void* l) {
    __builtin_amdgcn_global_load_lds(
        (const __attribute__((address_space(1))) void*)g,
        (__attribute__((address_space(3))) void*)l, 16, 0, 0);
}

// log_sigma scalar (true value 1.0 here). fp32 1.0 -> low 16 bits are 0x0000
// so the bf16 probe reads 0 and we fall through to the fp32 read.
DEV float read_ls(const void* p) {
    float vb = (float)((const bf16*)p)[0];
    if (vb != 0.0f && fabsf(vb) < 16.0f) return vb;
    float vf = ((const float*)p)[0];
    return (fabsf(vf) < 16.0f) ? vf : 0.0f;
}

#define MFMA16(a, b, c) __builtin_amdgcn_mfma_f32_16x16x32_bf16((a), (b), (c), 0, 0, 0)

// ws layout (bytes):
//   FX   @ 0        : [16384][128] bf16  (phi(x) rows 0..8191, phi(z) rows 8192..)
//   SQ   @ 4194304  : [16384] fp32 row sq-norms (of the rounded FX)
//   WB   @ 4259840  : [49152] bf16  = [w1 | w2 | w3 | sk]
//   BIAS @ 4358144  : [384] fp32    = [b1 | b2 | b3]
#define FX_OFF   0
#define SQ_OFF   4194304
#define WB_OFF   4259840
#define BIAS_OFF 4358144

// ---------------------------------------------------------------------------
// prep: convert weights (any dtype) -> bf16 WB, biases -> fp32 BIAS
// ---------------------------------------------------------------------------
__global__ __launch_bounds__(256) void prep_k(
    const void* __restrict__ w1, const void* __restrict__ b1,
    const void* __restrict__ w2, const void* __restrict__ b2,
    const void* __restrict__ w3, const void* __restrict__ b3,
    const void* __restrict__ sk,
    bf16* __restrict__ WB, float* __restrict__ BIAS)
{
    int tid = blockIdx.x * 256 + threadIdx.x;
    if (tid < 49152) {
        const void* s; int j;
        if (tid < 8192)       { s = w1; j = tid; }
        else if (tid < 24576) { s = w2; j = tid - 8192; }
        else if (tid < 40960) { s = w3; j = tid - 24576; }
        else                  { s = sk; j = tid - 40960; }
        bool isbf = detect_bf16(s);
        float v = isbf ? (float)((const bf16*)s)[j] : ((const float*)s)[j];
        WB[tid] = (bf16)v;
    } else if (tid < 49536) {
        int k = tid - 49152;
        const void* s = (k < 128) ? b1 : (k < 256) ? b2 : b3;
        int j = k & 127;
        bool isbf = detect_bf16(s);
        BIAS[k] = isbf ? (float)((const bf16*)s)[j] : ((const float*)s)[j];
    }
}

// ---------------------------------------------------------------------------
// Phase 1: fused 3-layer MLP + skip for 32 rows/block.
// H LDS row (stride 200 bf16): cols [0,128) = h, cols [128,192) = input row X
// (so layer3 folds the skip as concatenated K: C3 = [h2 | X] @ [W3 | Sk]^T).
// ---------------------------------------------------------------------------
#define HSTR 200

__global__ __launch_bounds__(256) void mlp_k(
    const void* __restrict__ xv, const void* __restrict__ zv,
    const bf16* __restrict__ WB, const float* __restrict__ BIAS,
    bf16* __restrict__ FX, float* __restrict__ SQ)
{
    __shared__ bf16 H[32 * HSTR];
    __shared__ float sqp[32][4];

    const int t    = threadIdx.x;
    const int lane = t & 63;
    const int w    = t >> 6;
    const int l15  = lane & 15;
    const int quad = lane >> 4;
    const int colw = w * 32;                 // this wave's 32 output cols
    const int row0 = blockIdx.x * 32;

    const void*  src   = (row0 < 8192) ? xv : zv;
    const size_t rbase = (row0 < 8192) ? (size_t)row0 * 64
                                       : (size_t)(row0 - 8192) * 64;
    const bool isbf = detect_bf16(src);

    // stage X tile (32 rows x 64) as bf16 into H[., 128..191]; 8 elems/thread
    {
        int r = t >> 3, g = t & 7;
        bf16 v8[8];
        if (isbf) {
            *(uint4*)v8 = *(const uint4*)((const bf16*)src + rbase + r * 64 + g * 8);
        } else {
            const float* f = (const float*)src + rbase + r * 64 + g * 8;
            float4 a = *(const float4*)f;
            float4 b = *(const float4*)(f + 4);
            v8[0] = (bf16)a.x; v8[1] = (bf16)a.y; v8[2] = (bf16)a.z; v8[3] = (bf16)a.w;
            v8[4] = (bf16)b.x; v8[5] = (bf16)b.y; v8[6] = (bf16)b.z; v8[7] = (bf16)b.w;
        }
        *(uint4*)&H[r * HSTR + 128 + g * 8] = *(uint4*)v8;
    }
    __syncthreads();

    const bf16* W1 = WB;
    const bf16* W2 = WB + 8192;
    const bf16* W3 = WB + 24576;
    const bf16* SK = WB + 40960;

    f32x4 acc[2][2];

    // ---------------- layer 1: K=64 (X region), B = w1 [128][64] -------------
    #pragma unroll
    for (int mi = 0; mi < 2; ++mi)
        #pragma unroll
        for (int ni = 0; ni < 2; ++ni)
            acc[mi][ni] = f32x4{0.f, 0.f, 0.f, 0.f};
    #pragma unroll
    for (int ks = 0; ks < 2; ++ks) {
        int ko = ks * 32 + quad * 8;
        bf16x8 a0 = *(const bf16x8*)&H[(l15)      * HSTR + 128 + ko];
        bf16x8 a1 = *(const bf16x8*)&H[(16 + l15) * HSTR + 128 + ko];
        bf16x8 bb0 = *(const bf16x8*)(W1 + (colw + l15)      * 64 + ko);
        bf16x8 bb1 = *(const bf16x8*)(W1 + (colw + 16 + l15) * 64 + ko);
        acc[0][0] = MFMA16(a0, bb0, acc[0][0]);
        acc[0][1] = MFMA16(a0, bb1, acc[0][1]);
        acc[1][0] = MFMA16(a1, bb0, acc[1][0]);
        acc[1][1] = MFMA16(a1, bb1, acc[1][1]);
    }
    {
        float bv0 = BIAS[colw + l15];
        float bv1 = BIAS[colw + 16 + l15];
        #pragma unroll
        for (int mi = 0; mi < 2; ++mi)
            #pragma unroll
            for (int p = 0; p < 4; ++p) {
                int r = mi * 16 + quad * 4 + p;
                H[r * HSTR + colw + l15]      = (bf16)fast_softplus(acc[mi][0][p] + bv0);
                H[r * HSTR + colw + 16 + l15] = (bf16)fast_softplus(acc[mi][1][p] + bv1);
            }
    }
    __syncthreads();

    // ---------------- layer 2: K=128 (h region), B = w2 [128][128] -----------
    #pragma unroll
    for (int mi = 0; mi < 2; ++mi)
        #pragma unroll
        for (int ni = 0; ni < 2; ++ni)
            acc[mi][ni] = f32x4{0.f, 0.f, 0.f, 0.f};
    #pragma unroll
    for (int ks = 0; ks < 4; ++ks) {
        int ko = ks * 32 + quad * 8;
        bf16x8 a0 = *(const bf16x8*)&H[(l15)      * HSTR + ko];
        bf16x8 a1 = *(const bf16x8*)&H[(16 + l15) * HSTR + ko];
        bf16x8 bb0 = *(const bf16x8*)(W2 + (colw + l15)      * 128 + ko);
        bf16x8 bb1 = *(const bf16x8*)(W2 + (colw + 16 + l15) * 128 + ko);
        acc[0][0] = MFMA16(a0, bb0, acc[0][0]);
        acc[0][1] = MFMA16(a0, bb1, acc[0][1]);
        acc[1][0] = MFMA16(a1, bb0, acc[1][0]);
        acc[1][1] = MFMA16(a1, bb1, acc[1][1]);
    }
    __syncthreads();   // all reads of h1 done before overwrite
    {
        float bv0 = BIAS[128 + colw + l15];
        float bv1 = BIAS[128 + colw + 16 + l15];
        #pragma unroll
        for (int mi = 0; mi < 2; ++mi)
            #pragma unroll
            for (int p = 0; p < 4; ++p) {
                int r = mi * 16 + quad * 4 + p;
                H[r * HSTR + colw + l15]      = (bf16)fast_softplus(acc[mi][0][p] + bv0);
                H[r * HSTR + colw + 16 + l15] = (bf16)fast_softplus(acc[mi][1][p] + bv1);
            }
    }
    __syncthreads();

    // ------- layer 3: K=192 ([h2 | X]), B = [w3 | skip_w], + b3 -> FX, SQ ----
    #pragma unroll
    for (int mi = 0; mi < 2; ++mi)
        #pragma unroll
        for (int ni = 0; ni < 2; ++ni)
            acc[mi][ni] = f32x4{0.f, 0.f, 0.f, 0.f};
    #pragma unroll
    for (int ks = 0; ks < 6; ++ks) {
        int ko = ks * 32 + quad * 8;
        bf16x8 a0 = *(const bf16x8*)&H[(l15)      * HSTR + ko];
        bf16x8 a1 = *(const bf16x8*)&H[(16 + l15) * HSTR + ko];
        const bf16 *p0, *p1;
        if (ks < 4) {
            p0 = W3 + (colw + l15)      * 128 + ko;
            p1 = W3 + (colw + 16 + l15) * 128 + ko;
        } else {
            int ko2 = (ks - 4) * 32 + quad * 8;
            p0 = SK + (colw + l15)      * 64 + ko2;
            p1 = SK + (colw + 16 + l15) * 64 + ko2;
        }
        bf16x8 bb0 = *(const bf16x8*)p0;
        bf16x8 bb1 = *(const bf16x8*)p1;
        acc[0][0] = MFMA16(a0, bb0, acc[0][0]);
        acc[0][1] = MFMA16(a0, bb1, acc[0][1]);
        acc[1][0] = MFMA16(a1, bb0, acc[1][0]);
        acc[1][1] = MFMA16(a1, bb1, acc[1][1]);
    }
    {
        float bv0 = BIAS[256 + colw + l15];
        float bv1 = BIAS[256 + colw + 16 + l15];
        #pragma unroll
        for (int mi = 0; mi < 2; ++mi)
            #pragma unroll
            for (int p = 0; p < 4; ++p) {
                int r = mi * 16 + quad * 4 + p;
                float v0 = acc[mi][0][p] + bv0;
                float v1 = acc[mi][1][p] + bv1;
                bf16 q0 = (bf16)v0, q1 = (bf16)v1;
                FX[(size_t)(row0 + r) * 128 + colw + l15]      = q0;
                FX[(size_t)(row0 + r) * 128 + colw + 16 + l15] = q1;
                // sq from the *rounded* values so diff is an exact sq-distance
                float f0 = (float)q0, f1 = (float)q1;
                float s = fmaf(f0, f0, f1 * f1);
                s += __shfl_xor(s, 1, 16);
                s += __shfl_xor(s, 2, 16);
                s += __shfl_xor(s, 4, 16);
                s += __shfl_xor(s, 8, 16);
                if (l15 == 0) sqp[r][w] = s;
            }
    }
    __syncthreads();
    if (t < 32) SQ[row0 + t] = sqp[t][0] + sqp[t][1] + sqp[t][2] + sqp[t][3];
}

// ---------------------------------------------------------------------------
// Phase 2: 128x128 C-tile per block, K=128 staged once via global_load_lds.
// XOR-chunk swizzle on the GLOBAL fetch side: LDS chunk (r,c) holds global
// chunk (r, c^(r&7)); fragment reads un-swizzle with the same XOR.
//
// MFMA operands are SWAPPED (B-frag first): A/B fragment layouts of
// mfma_f32_16x16x32_bf16 are symmetric, and C/D layout is col=lane&15,
// row=(lane>>4)*4+reg. With the swap, lane&15 indexes the OUTPUT ROW and the
// 4 acc regs are 4 CONSECUTIVE OUTPUT COLUMNS -> one global_store_dwordx4
// (16 B/lane) per fragment instead of 4 scalar row-strided stores.
// NOTE: stores are PLAIN (not nontemporal). Lanes of a quad hit 16 different
// rows (64B segments of distinct 128B lines); L2 write-combining is what
// merges the two adjacent 64B halves from consecutive ni iterations into
// full lines. nt bypassed L2 and cost ~14 us (round-1 post-mortem).
// ---------------------------------------------------------------------------
__global__ __launch_bounds__(256) void ker_k(
    const bf16* __restrict__ FX, const float* __restrict__ SQ,
    const void* __restrict__ lsp, const void* __restrict__ w1p,
    void* __restrict__ outv)
{
    __shared__ bf16 AT[128 * 128];
    __shared__ bf16 BT[128 * 128];

    const int t    = threadIdx.x;
    const int lane = t & 63;
    const int w    = t >> 6;
    const int l15  = lane & 15;
    const int quad = lane >> 4;
    const int wm   = w >> 1, wn = w & 1;
    const int brow = blockIdx.y, bcol = blockIdx.x;

    const bf16* Ag = FX + (size_t)brow * 128 * 128;            // fx tile
    const bf16* Bg = FX + (size_t)(8192 + bcol * 128) * 128;   // fz tile
    #pragma unroll
    for (int i = 0; i < 8; ++i) {
        int slot = (w * 8 + i) * 64 + lane;        // 16B-chunk slot in LDS
        int r = slot >> 4, c = slot & 15;
        int gc = (r << 4) | (c ^ (r & 7));         // swizzled source chunk
        async_lds16(Ag + gc * 8, &AT[(w * 8 + i) * 512]);
        async_lds16(Bg + gc * 8, &BT[(w * 8 + i) * 512]);
    }
    __syncthreads();

    f32x4 acc[4][4];
    #pragma unroll
    for (int mi = 0; mi < 4; ++mi)
        #pragma unroll
        for (int ni = 0; ni < 4; ++ni)
            acc[mi][ni] = f32x4{0.f, 0.f, 0.f, 0.f};

    #pragma unroll
    for (int ks = 0; ks < 4; ++ks) {
        bf16x8 a[4], b[4];
        #pragma unroll
        for (int mi = 0; mi < 4; ++mi) {
            int r  = wm * 64 + mi * 16 + l15;
            int cc = (ks * 4 + quad) ^ (r & 7);
            a[mi] = *(const bf16x8*)&AT[r * 128 + cc * 8];
        }
        #pragma unroll
        for (int ni = 0; ni < 4; ++ni) {
            int r  = wn * 64 + ni * 16 + l15;
            int cc = (ks * 4 + quad) ^ (r & 7);
            b[ni] = *(const bf16x8*)&BT[r * 128 + cc * 8];
        }
        // swapped operand order: D[row=fz-idx in regs][col=fx-idx at l15]
        // -> acc[mi][ni][p] = dot(FX row wm*64+mi*16+l15,
        //                         FZ row wn*64+ni*16+quad*4+p)
        #pragma unroll
        for (int mi = 0; mi < 4; ++mi)
            #pragma unroll
            for (int ni = 0; ni < 4; ++ni)
                acc[mi][ni] = MFMA16(b[ni], a[mi], acc[mi][ni]);
    }

    // epilogue: out = exp2(c2*sqx + c2*sqz - 2*c2*dot),  c2 = inv_bw*log2(e)
    const bool isbf = detect_bf16(w1p);   // output dtype follows problem dtype
    float ls  = read_ls(lsp);
    float p10 = __builtin_amdgcn_exp2f(ls * 3.321928094887362f);   // 10^ls
    float c2  = (-0.5f / p10) * 1.4426950408889634f;
    float m2  = -2.0f * c2;
    const float* sqx = SQ + (size_t)brow * 128;
    const float* sqz = SQ + 8192 + (size_t)bcol * 128;

    #pragma unroll
    for (int mi = 0; mi < 4; ++mi) {
        int rl = wm * 64 + mi * 16 + l15;               // per-lane output row
        float cq = c2 * sqx[rl];
        size_t grow = (size_t)(brow * 128 + rl) * 8192;
        #pragma unroll
        for (int ni = 0; ni < 4; ++ni) {
            int clb  = wn * 64 + ni * 16 + quad * 4;    // 4-col base
            int gcol = bcol * 128 + clb;
            f32x4 qz = *(const f32x4*)&sqz[clb];
            float e0 = __builtin_amdgcn_exp2f(fmaf(m2, acc[mi][ni][0], fmaf(c2, qz[0], cq)));
            float e1 = __builtin_amdgcn_exp2f(fmaf(m2, acc[mi][ni][1], fmaf(c2, qz[1], cq)));
            float e2 = __builtin_amdgcn_exp2f(fmaf(m2, acc[mi][ni][2], fmaf(c2, qz[2], cq)));
            float e3 = __builtin_amdgcn_exp2f(fmaf(m2, acc[mi][ni][3], fmaf(c2, qz[3], cq)));
            if (isbf) {
                bf16* o = (bf16*)outv;
                bf16x4 pv = { (bf16)e0, (bf16)e1, (bf16)e2, (bf16)e3 };
                *(bf16x4*)(o + grow + gcol) = pv;
            } else {
                float* o = (float*)outv;
                f32x4 ev = { e0, e1, e2, e3 };
                *(f32x4*)(o + grow + gcol) = ev;
            }
        }
    }
}

extern "C" void kernel_launch(void* const* d_in, const int* in_sizes, int n_in,
                              void* d_out, int out_size, void* d_ws, size_t ws_size,
                              hipStream_t stream) {
    bf16*  FX   = (bf16*) ((char*)d_ws + FX_OFF);
    float* SQ   = (float*)((char*)d_ws + SQ_OFF);
    bf16*  WB   = (bf16*) ((char*)d_ws + WB_OFF);
    float* BIAS = (float*)((char*)d_ws + BIAS_OFF);

    prep_k<<<194, 256, 0, stream>>>(d_in[2], d_in[3], d_in[4], d_in[5],
                                    d_in[6], d_in[7], d_in[8], WB, BIAS);
    mlp_k<<<512, 256, 0, stream>>>(d_in[0], d_in[1], WB, BIAS, FX, SQ);
    ker_k<<<dim3(64, 64), 256, 0, stream>>>(FX, SQ, d_in[9], d_in[2], d_out);
}

// Round 3
// 300.392 us; speedup vs baseline: 1.0554x; 1.0331x over previous
//
#include <hip/hip_runtime.h>
#include <hip/hip_bf16.h>
#include <stdint.h>

typedef __bf16 bf16;
typedef __bf16 bf16x8 __attribute__((ext_vector_type(8)));
typedef __bf16 bf16x4 __attribute__((ext_vector_type(4)));
typedef float f32x4 __attribute__((ext_vector_type(4)));

#define DEV static __device__ __forceinline__

// ---------------------------------------------------------------------------
// dtype detector: bf16 tensors have ~all uint16 exponent fields near 127;
// fp32 tensors look bf16-like only in the top halves (~50%) plus ~7% noise.
// bf16 -> cnt ~63/64 ; fp32 -> cnt ~34/64. Threshold 50.
// ---------------------------------------------------------------------------
DEV bool detect_bf16(const void* p) {
    const uint16_t* u = (const uint16_t*)p;
    int cnt = 0;
    #pragma unroll
    for (int i = 0; i < 64; ++i) {
        int e = (u[i] >> 7) & 0xFF;          // bf16 exponent field
        cnt += (e >= 116 && e <= 134) ? 1 : 0;
    }
    return cnt >= 50;
}

DEV float fast_softplus(float v) {
    // softplus(v) = max(v,0) + log1p(exp(-|v|)), via exp2/log2 HW ops
    float e = __builtin_amdgcn_exp2f(fabsf(v) * -1.4426950408889634f);
    float l = __builtin_amdgcn_logf(1.0f + e) * 0.6931471805599453f;
    return fmaxf(v, 0.0f) + l;
}

DEV void async_lds16(const void* g, void* l) {
    __builtin_amdgcn_global_load_lds(
        (const __attribute__((address_space(1))) void*)g,
        (__attribute__((address_space(3))) void*)l, 16, 0, 0);
}

// log_sigma scalar (true value 1.0 here). fp32 1.0 -> low 16 bits are 0x0000
// so the bf16 probe reads 0 and we fall through to the fp32 read.
DEV float read_ls(const void* p) {
    float vb = (float)((const bf16*)p)[0];
    if (vb != 0.0f && fabsf(vb) < 16.0f) return vb;
    float vf = ((const float*)p)[0];
    return (fabsf(vf) < 16.0f) ? vf : 0.0f;
}

#define MFMA16(a, b, c) __builtin_amdgcn_mfma_f32_16x16x32_bf16((a), (b), (c), 0, 0, 0)

// ws layout (bytes):
//   FX   @ 0        : [16384][128] bf16  (phi(x) rows 0..8191, phi(z) rows 8192..)
//   SQ   @ 4194304  : [16384] fp32 row sq-norms (of the rounded FX)
//   WB   @ 4259840  : [49152] bf16  = [w1 | w2 | w3 | sk]
//   BIAS @ 4358144  : [384] fp32    = [b1 | b2 | b3]
#define FX_OFF   0
#define SQ_OFF   4194304
#define WB_OFF   4259840
#define BIAS_OFF 4358144

// ---------------------------------------------------------------------------
// prep: convert weights (any dtype) -> bf16 WB, biases -> fp32 BIAS
// ---------------------------------------------------------------------------
__global__ __launch_bounds__(256) void prep_k(
    const void* __restrict__ w1, const void* __restrict__ b1,
    const void* __restrict__ w2, const void* __restrict__ b2,
    const void* __restrict__ w3, const void* __restrict__ b3,
    const void* __restrict__ sk,
    bf16* __restrict__ WB, float* __restrict__ BIAS)
{
    int tid = blockIdx.x * 256 + threadIdx.x;
    if (tid < 49152) {
        const void* s; int j;
        if (tid < 8192)       { s = w1; j = tid; }
        else if (tid < 24576) { s = w2; j = tid - 8192; }
        else if (tid < 40960) { s = w3; j = tid - 24576; }
        else                  { s = sk; j = tid - 40960; }
        bool isbf = detect_bf16(s);
        float v = isbf ? (float)((const bf16*)s)[j] : ((const float*)s)[j];
        WB[tid] = (bf16)v;
    } else if (tid < 49536) {
        int k = tid - 49152;
        const void* s = (k < 128) ? b1 : (k < 256) ? b2 : b3;
        int j = k & 127;
        bool isbf = detect_bf16(s);
        BIAS[k] = isbf ? (float)((const bf16*)s)[j] : ((const float*)s)[j];
    }
}

// ---------------------------------------------------------------------------
// Phase 1: fused 3-layer MLP + skip for 32 rows/block.
// H LDS row (stride 200 bf16): cols [0,128) = h, cols [128,192) = input row X
// (so layer3 folds the skip as concatenated K: C3 = [h2 | X] @ [W3 | Sk]^T).
// ---------------------------------------------------------------------------
#define HSTR 200

__global__ __launch_bounds__(256) void mlp_k(
    const void* __restrict__ xv, const void* __restrict__ zv,
    const bf16* __restrict__ WB, const float* __restrict__ BIAS,
    bf16* __restrict__ FX, float* __restrict__ SQ)
{
    __shared__ bf16 H[32 * HSTR];
    __shared__ float sqp[32][4];

    const int t    = threadIdx.x;
    const int lane = t & 63;
    const int w    = t >> 6;
    const int l15  = lane & 15;
    const int quad = lane >> 4;
    const int colw = w * 32;                 // this wave's 32 output cols
    const int row0 = blockIdx.x * 32;

    const void*  src   = (row0 < 8192) ? xv : zv;
    const size_t rbase = (row0 < 8192) ? (size_t)row0 * 64
                                       : (size_t)(row0 - 8192) * 64;
    const bool isbf = detect_bf16(src);

    // stage X tile (32 rows x 64) as bf16 into H[., 128..191]; 8 elems/thread
    {
        int r = t >> 3, g = t & 7;
        bf16 v8[8];
        if (isbf) {
            *(uint4*)v8 = *(const uint4*)((const bf16*)src + rbase + r * 64 + g * 8);
        } else {
            const float* f = (const float*)src + rbase + r * 64 + g * 8;
            float4 a = *(const float4*)f;
            float4 b = *(const float4*)(f + 4);
            v8[0] = (bf16)a.x; v8[1] = (bf16)a.y; v8[2] = (bf16)a.z; v8[3] = (bf16)a.w;
            v8[4] = (bf16)b.x; v8[5] = (bf16)b.y; v8[6] = (bf16)b.z; v8[7] = (bf16)b.w;
        }
        *(uint4*)&H[r * HSTR + 128 + g * 8] = *(uint4*)v8;
    }
    __syncthreads();

    const bf16* W1 = WB;
    const bf16* W2 = WB + 8192;
    const bf16* W3 = WB + 24576;
    const bf16* SK = WB + 40960;

    f32x4 acc[2][2];

    // ---------------- layer 1: K=64 (X region), B = w1 [128][64] -------------
    #pragma unroll
    for (int mi = 0; mi < 2; ++mi)
        #pragma unroll
        for (int ni = 0; ni < 2; ++ni)
            acc[mi][ni] = f32x4{0.f, 0.f, 0.f, 0.f};
    #pragma unroll
    for (int ks = 0; ks < 2; ++ks) {
        int ko = ks * 32 + quad * 8;
        bf16x8 a0 = *(const bf16x8*)&H[(l15)      * HSTR + 128 + ko];
        bf16x8 a1 = *(const bf16x8*)&H[(16 + l15) * HSTR + 128 + ko];
        bf16x8 bb0 = *(const bf16x8*)(W1 + (colw + l15)      * 64 + ko);
        bf16x8 bb1 = *(const bf16x8*)(W1 + (colw + 16 + l15) * 64 + ko);
        acc[0][0] = MFMA16(a0, bb0, acc[0][0]);
        acc[0][1] = MFMA16(a0, bb1, acc[0][1]);
        acc[1][0] = MFMA16(a1, bb0, acc[1][0]);
        acc[1][1] = MFMA16(a1, bb1, acc[1][1]);
    }
    {
        float bv0 = BIAS[colw + l15];
        float bv1 = BIAS[colw + 16 + l15];
        #pragma unroll
        for (int mi = 0; mi < 2; ++mi)
            #pragma unroll
            for (int p = 0; p < 4; ++p) {
                int r = mi * 16 + quad * 4 + p;
                H[r * HSTR + colw + l15]      = (bf16)fast_softplus(acc[mi][0][p] + bv0);
                H[r * HSTR + colw + 16 + l15] = (bf16)fast_softplus(acc[mi][1][p] + bv1);
            }
    }
    __syncthreads();

    // ---------------- layer 2: K=128 (h region), B = w2 [128][128] -----------
    #pragma unroll
    for (int mi = 0; mi < 2; ++mi)
        #pragma unroll
        for (int ni = 0; ni < 2; ++ni)
            acc[mi][ni] = f32x4{0.f, 0.f, 0.f, 0.f};
    #pragma unroll
    for (int ks = 0; ks < 4; ++ks) {
        int ko = ks * 32 + quad * 8;
        bf16x8 a0 = *(const bf16x8*)&H[(l15)      * HSTR + ko];
        bf16x8 a1 = *(const bf16x8*)&H[(16 + l15) * HSTR + ko];
        bf16x8 bb0 = *(const bf16x8*)(W2 + (colw + l15)      * 128 + ko);
        bf16x8 bb1 = *(const bf16x8*)(W2 + (colw + 16 + l15) * 128 + ko);
        acc[0][0] = MFMA16(a0, bb0, acc[0][0]);
        acc[0][1] = MFMA16(a0, bb1, acc[0][1]);
        acc[1][0] = MFMA16(a1, bb0, acc[1][0]);
        acc[1][1] = MFMA16(a1, bb1, acc[1][1]);
    }
    __syncthreads();   // all reads of h1 done before overwrite
    {
        float bv0 = BIAS[128 + colw + l15];
        float bv1 = BIAS[128 + colw + 16 + l15];
        #pragma unroll
        for (int mi = 0; mi < 2; ++mi)
            #pragma unroll
            for (int p = 0; p < 4; ++p) {
                int r = mi * 16 + quad * 4 + p;
                H[r * HSTR + colw + l15]      = (bf16)fast_softplus(acc[mi][0][p] + bv0);
                H[r * HSTR + colw + 16 + l15] = (bf16)fast_softplus(acc[mi][1][p] + bv1);
            }
    }
    __syncthreads();

    // ------- layer 3: K=192 ([h2 | X]), B = [w3 | skip_w], + b3 -> FX, SQ ----
    #pragma unroll
    for (int mi = 0; mi < 2; ++mi)
        #pragma unroll
        for (int ni = 0; ni < 2; ++ni)
            acc[mi][ni] = f32x4{0.f, 0.f, 0.f, 0.f};
    #pragma unroll
    for (int ks = 0; ks < 6; ++ks) {
        int ko = ks * 32 + quad * 8;
        bf16x8 a0 = *(const bf16x8*)&H[(l15)      * HSTR + ko];
        bf16x8 a1 = *(const bf16x8*)&H[(16 + l15) * HSTR + ko];
        const bf16 *p0, *p1;
        if (ks < 4) {
            p0 = W3 + (colw + l15)      * 128 + ko;
            p1 = W3 + (colw + 16 + l15) * 128 + ko;
        } else {
            int ko2 = (ks - 4) * 32 + quad * 8;
            p0 = SK + (colw + l15)      * 64 + ko2;
            p1 = SK + (colw + 16 + l15) * 64 + ko2;
        }
        bf16x8 bb0 = *(const bf16x8*)p0;
        bf16x8 bb1 = *(const bf16x8*)p1;
        acc[0][0] = MFMA16(a0, bb0, acc[0][0]);
        acc[0][1] = MFMA16(a0, bb1, acc[0][1]);
        acc[1][0] = MFMA16(a1, bb0, acc[1][0]);
        acc[1][1] = MFMA16(a1, bb1, acc[1][1]);
    }
    {
        float bv0 = BIAS[256 + colw + l15];
        float bv1 = BIAS[256 + colw + 16 + l15];
        #pragma unroll
        for (int mi = 0; mi < 2; ++mi)
            #pragma unroll
            for (int p = 0; p < 4; ++p) {
                int r = mi * 16 + quad * 4 + p;
                float v0 = acc[mi][0][p] + bv0;
                float v1 = acc[mi][1][p] + bv1;
                bf16 q0 = (bf16)v0, q1 = (bf16)v1;
                FX[(size_t)(row0 + r) * 128 + colw + l15]      = q0;
                FX[(size_t)(row0 + r) * 128 + colw + 16 + l15] = q1;
                // sq from the *rounded* values so diff is an exact sq-distance
                float f0 = (float)q0, f1 = (float)q1;
                float s = fmaf(f0, f0, f1 * f1);
                s += __shfl_xor(s, 1, 16);
                s += __shfl_xor(s, 2, 16);
                s += __shfl_xor(s, 4, 16);
                s += __shfl_xor(s, 8, 16);
                if (l15 == 0) sqp[r][w] = s;
            }
    }
    __syncthreads();
    if (t < 32) SQ[row0 + t] = sqp[t][0] + sqp[t][1] + sqp[t][2] + sqp[t][3];
}

// ---------------------------------------------------------------------------
// Phase 2: 128x128 C-tile per block. K=128 is processed in TWO 64-wide halves
// through a 32 KB LDS footprint (AT/BT = [128][64] bf16 = 16 KB each), with
// acc carried across halves. Rationale: 64 KB/block allowed only 2 blocks/CU,
// so the per-block serial phases (stage -> MFMA -> 64 KB store drain) could
// not overlap across blocks; 32 KB + __launch_bounds__(256,4) gives 4
// blocks/CU so one block's store drain hides under others' stage/compute.
// XOR-chunk swizzle on the GLOBAL fetch side (per half): LDS chunk (r,c),
// c in 0..7, holds global col-chunk h*8 + (c ^ (r&7)); fragment reads
// un-swizzle with the same XOR. Bank check: byte = r*128 + cc*16 -> bank
// depends only on cc (4cc..4cc+3), cc spans 0..7 across quads/rows; only
// l15 vs l15+8 alias (2-way, free per m136).
//
// MFMA operands SWAPPED (B-frag first): C/D layout col=lane&15,
// row=(lane>>4)*4+reg, so lane&15 indexes the OUTPUT ROW and the 4 acc regs
// are 4 consecutive OUTPUT COLUMNS -> one dwordx4 store per fragment.
// Plain stores (nt cost ~14 us in round 1 — L2 write-combining needed).
// ---------------------------------------------------------------------------
__global__ __launch_bounds__(256, 4) void ker_k(
    const bf16* __restrict__ FX, const float* __restrict__ SQ,
    const void* __restrict__ lsp, const void* __restrict__ w1p,
    void* __restrict__ outv)
{
    __shared__ bf16 AT[128 * 64];
    __shared__ bf16 BT[128 * 64];

    const int t    = threadIdx.x;
    const int lane = t & 63;
    const int w    = t >> 6;
    const int l15  = lane & 15;
    const int quad = lane >> 4;
    const int wm   = w >> 1, wn = w & 1;
    const int brow = blockIdx.y, bcol = blockIdx.x;

    const bf16* Ag = FX + (size_t)brow * 128 * 128;            // fx tile
    const bf16* Bg = FX + (size_t)(8192 + bcol * 128) * 128;   // fz tile

    f32x4 acc[4][4];
    #pragma unroll
    for (int mi = 0; mi < 4; ++mi)
        #pragma unroll
        for (int ni = 0; ni < 4; ++ni)
            acc[mi][ni] = f32x4{0.f, 0.f, 0.f, 0.f};

    #pragma unroll
    for (int h = 0; h < 2; ++h) {
        // ---- stage half h: tile [128 rows][64 cols] = 1024 16B-chunks each
        #pragma unroll
        for (int i = 0; i < 4; ++i) {
            int slot = (w * 4 + i) * 64 + lane;      // 0..1023
            int r = slot >> 3, c = slot & 7;
            int gc = (r << 4) + h * 8 + (c ^ (r & 7));   // global 16B-chunk
            async_lds16(Ag + gc * 8, &AT[slot * 8]);
            async_lds16(Bg + gc * 8, &BT[slot * 8]);
        }
        __syncthreads();

        #pragma unroll
        for (int ksub = 0; ksub < 2; ++ksub) {
            bf16x8 a[4], b[4];
            #pragma unroll
            for (int mi = 0; mi < 4; ++mi) {
                int r  = wm * 64 + mi * 16 + l15;
                int cc = (ksub * 4 + quad) ^ (r & 7);
                a[mi] = *(const bf16x8*)&AT[r * 64 + cc * 8];
            }
            #pragma unroll
            for (int ni = 0; ni < 4; ++ni) {
                int r  = wn * 64 + ni * 16 + l15;
                int cc = (ksub * 4 + quad) ^ (r & 7);
                b[ni] = *(const bf16x8*)&BT[r * 64 + cc * 8];
            }
            // swapped operand order: acc[mi][ni][p] =
            //   dot(FX row wm*64+mi*16+l15, FZ row wn*64+ni*16+quad*4+p)
            #pragma unroll
            for (int mi = 0; mi < 4; ++mi)
                #pragma unroll
                for (int ni = 0; ni < 4; ++ni)
                    acc[mi][ni] = MFMA16(b[ni], a[mi], acc[mi][ni]);
        }
        if (h == 0) __syncthreads();   // all reads done before overwrite
    }

    // epilogue: out = exp2(c2*sqx + c2*sqz - 2*c2*dot),  c2 = inv_bw*log2(e)
    const bool isbf = detect_bf16(w1p);   // output dtype follows problem dtype
    float ls  = read_ls(lsp);
    float p10 = __builtin_amdgcn_exp2f(ls * 3.321928094887362f);   // 10^ls
    float c2  = (-0.5f / p10) * 1.4426950408889634f;
    float m2  = -2.0f * c2;
    const float* sqx = SQ + (size_t)brow * 128;
    const float* sqz = SQ + 8192 + (size_t)bcol * 128;

    #pragma unroll
    for (int mi = 0; mi < 4; ++mi) {
        int rl = wm * 64 + mi * 16 + l15;               // per-lane output row
        float cq = c2 * sqx[rl];
        size_t grow = (size_t)(brow * 128 + rl) * 8192;
        #pragma unroll
        for (int ni = 0; ni < 4; ++ni) {
            int clb  = wn * 64 + ni * 16 + quad * 4;    // 4-col base
            int gcol = bcol * 128 + clb;
            f32x4 qz = *(const f32x4*)&sqz[clb];
            float e0 = __builtin_amdgcn_exp2f(fmaf(m2, acc[mi][ni][0], fmaf(c2, qz[0], cq)));
            float e1 = __builtin_amdgcn_exp2f(fmaf(m2, acc[mi][ni][1], fmaf(c2, qz[1], cq)));
            float e2 = __builtin_amdgcn_exp2f(fmaf(m2, acc[mi][ni][2], fmaf(c2, qz[2], cq)));
            float e3 = __builtin_amdgcn_exp2f(fmaf(m2, acc[mi][ni][3], fmaf(c2, qz[3], cq)));
            if (isbf) {
                bf16* o = (bf16*)outv;
                bf16x4 pv = { (bf16)e0, (bf16)e1, (bf16)e2, (bf16)e3 };
                *(bf16x4*)(o + grow + gcol) = pv;
            } else {
                float* o = (float*)outv;
                f32x4 ev = { e0, e1, e2, e3 };
                *(f32x4*)(o + grow + gcol) = ev;
            }
        }
    }
}

extern "C" void kernel_launch(void* const* d_in, const int* in_sizes, int n_in,
                              void* d_out, int out_size, void* d_ws, size_t ws_size,
                              hipStream_t stream) {
    bf16*  FX   = (bf16*) ((char*)d_ws + FX_OFF);
    float* SQ   = (float*)((char*)d_ws + SQ_OFF);
    bf16*  WB   = (bf16*) ((char*)d_ws + WB_OFF);
    float* BIAS = (float*)((char*)d_ws + BIAS_OFF);

    prep_k<<<194, 256, 0, stream>>>(d_in[2], d_in[3], d_in[4], d_in[5],
                                    d_in[6], d_in[7], d_in[8], WB, BIAS);
    mlp_k<<<512, 256, 0, stream>>>(d_in[0], d_in[1], WB, BIAS, FX, SQ);
    ker_k<<<dim3(64, 64), 256, 0, stream>>>(FX, SQ, d_in[9], d_in[2], d_out);
}